// Round 1
// baseline (281.440 us; speedup 1.0000x reference)
//
#include <hip/hip_runtime.h>

#define NSENT 64
#define NCAND 8192
#define LMAX  512
#define KOUT  128
#define TPB   512

__global__ __launch_bounds__(TPB) void extract_spans_kernel(
    const float* __restrict__ scores,
    const int*   __restrict__ starts,
    const int*   __restrict__ ends,
    int*         __restrict__ out)
{
    // Exactly 64 KiB static LDS: 8192 x u64 sort keys.
    // After the greedy phase the buffer is dead and is reused (aliased) for
    // the 128-element final rank-sort.
    __shared__ unsigned long long keys[NCAND];

    const int  sent = blockIdx.x;
    const int  tid  = threadIdx.x;
    const long base = (long)sent * NCAND;

    // ---- 1. Build 64-bit sort keys (coalesced loads) -----------------------
    // high 32: descending-orderable score bits; low 31: (idx<<18)|(st<<9)|en
    // Ascending sort of this key == stable argsort(-scores) (ties -> idx asc).
    for (int i = tid; i < NCAND; i += TPB) {
        unsigned u = __float_as_uint(scores[base + i]);
        unsigned o = (u & 0x80000000u) ? ~u : (u | 0x80000000u); // ascending-orderable
        unsigned d = ~o;                                          // descending
        unsigned st = (unsigned)starts[base + i];
        unsigned en = (unsigned)ends[base + i];
        unsigned payload = ((unsigned)i << 18) | (st << 9) | en;
        keys[i] = ((unsigned long long)d << 32) | payload;
    }

    // ---- 2. Bitonic sort (ascending) in LDS --------------------------------
    for (int k = 2; k <= NCAND; k <<= 1) {
        for (int j = k >> 1; j > 0; j >>= 1) {
            __syncthreads();
            for (int p = tid; p < NCAND / 2; p += TPB) {
                int low = p & (j - 1);
                int i   = ((p - low) << 1) | low;  // insert 0-bit at position log2(j)
                int q   = i | j;
                unsigned long long a = keys[i];
                unsigned long long b = keys[q];
                bool up = ((i & k) == 0);
                if ((a > b) == up) { keys[i] = b; keys[q] = a; }
            }
        }
    }
    __syncthreads();

    // ---- 3. Greedy non-crossing selection: wave 0 only ---------------------
    // Accepted spans live in registers: lane L holds selection slots L (selA)
    // and 64+L (selB). Crossing test: candidate (st,en) crosses accepted
    // (as,ae) iff (st<as && as<=en && ae>en) || (as<st && ae>=st && ae<en).
    // Each lane checks its own <=2 accepted spans; __any combines.
    unsigned int* selbuf = (unsigned int*)keys;   // aliased reuse (post-greedy)

    if (tid < 64) {
        const int lane = tid;
        unsigned selA = 0u, selB = 0u;
        int n = 0;
        for (int it = 0; it < NCAND; ++it) {
            unsigned pay = (unsigned)keys[it];    // uniform-address LDS broadcast
            int en = (int)(pay & 511u);
            int st = (int)((pay >> 9) & 511u);

            bool c = false;
            if (lane < n) {
                int as = (int)((selA >> 9) & 511u), ae = (int)(selA & 511u);
                c |= (st < as && as <= en && ae > en) || (as < st && ae >= st && ae < en);
            }
            if (64 + lane < n) {
                int as = (int)((selB >> 9) & 511u), ae = (int)(selB & 511u);
                c |= (st < as && as <= en && ae > en) || (as < st && ae >= st && ae < en);
            }
            if (!__any((int)c)) {
                if ((n & 63) == lane) {
                    if (n < 64) selA = pay; else selB = pay;
                }
                ++n;
                if (n == KOUT) break;   // state frozen in reference past this point
            }
        }

        // Tail-fill unfilled slots with slot 0's payload (matches reference),
        // then stage payloads + composite sort keys into reused LDS.
        unsigned p0 = (unsigned)__shfl((int)selA, 0);
        unsigned a  = (lane      < n) ? selA : p0;
        unsigned b  = (64 + lane < n) ? selB : p0;
        selbuf[lane]            = a;
        selbuf[64 + lane]       = b;
        // sort key = (st*512+en)<<7 | slot   (slot = stable tie-break)
        selbuf[128 + lane]      = ((a & 0x3FFFFu) << 7) | (unsigned)lane;
        selbuf[128 + 64 + lane] = ((b & 0x3FFFFu) << 7) | (unsigned)(64 + lane);
    }
    __syncthreads();

    // ---- 4. Rank-sort the 128 selected, write int32 output -----------------
    if (tid < KOUT) {
        unsigned pay = selbuf[tid];
        unsigned mk  = selbuf[128 + tid];
        int rank = 0;
        for (int t2 = 0; t2 < KOUT; ++t2)
            rank += (selbuf[128 + t2] < mk) ? 1 : 0;
        out[sent * KOUT + rank] = (int)(pay >> 18);
    }
}

extern "C" void kernel_launch(void* const* d_in, const int* in_sizes, int n_in,
                              void* d_out, int out_size, void* d_ws, size_t ws_size,
                              hipStream_t stream) {
    const float* scores = (const float*)d_in[0];
    const int*   starts = (const int*)d_in[1];
    const int*   ends   = (const int*)d_in[2];
    int*         out    = (int*)d_out;

    extract_spans_kernel<<<NSENT, TPB, 0, stream>>>(scores, starts, ends, out);
}

// Round 2
// 250.611 us; speedup vs baseline: 1.1230x; 1.1230x over previous
//
#include <hip/hip_runtime.h>

#define NSENT 64
#define NCAND 8192
#define LMAX  512
#define KOUT  128
#define TPB   512

__global__ __launch_bounds__(TPB) void extract_spans_kernel(
    const float* __restrict__ scores,
    const int*   __restrict__ starts,
    const int*   __restrict__ ends,
    int*         __restrict__ out)
{
    // 64 KiB: 8192 x u64 sort keys (score-desc in high 32, payload in low 31).
    __shared__ unsigned long long keys[NCAND];
    __shared__ unsigned acc_list[KOUT];          // accepted payloads, in accept order
    __shared__ unsigned long long amask[TPB/64]; // per-window alive mask (8 waves)
    __shared__ unsigned mkbuf[KOUT];             // final-sort composite keys
    __shared__ unsigned paybuf[KOUT];

    const int  sent = blockIdx.x;
    const int  tid  = threadIdx.x;
    const long base = (long)sent * NCAND;

    // ---- 1. Build 64-bit sort keys (coalesced) -----------------------------
    for (int i = tid; i < NCAND; i += TPB) {
        unsigned u = __float_as_uint(scores[base + i]);
        unsigned o = (u & 0x80000000u) ? ~u : (u | 0x80000000u); // ascending-orderable
        unsigned d = ~o;                                          // descending
        unsigned st = (unsigned)starts[base + i];
        unsigned en = (unsigned)ends[base + i];
        unsigned payload = ((unsigned)i << 18) | (st << 9) | en;
        keys[i] = ((unsigned long long)d << 32) | payload;
    }

    // ---- 2. Bitonic sort (ascending) in LDS --------------------------------
    for (int k = 2; k <= NCAND; k <<= 1) {
        for (int j = k >> 1; j > 0; j >>= 1) {
            __syncthreads();
            for (int p = tid; p < NCAND / 2; p += TPB) {
                int low = p & (j - 1);
                int i   = ((p - low) << 1) | low;
                int q   = i | j;
                unsigned long long a = keys[i];
                unsigned long long b = keys[q];
                bool up = ((i & k) == 0);
                if ((a > b) == up) { keys[i] = b; keys[q] = a; }
            }
        }
    }
    __syncthreads();

    // ---- 3. Greedy non-crossing selection, window-parallel -----------------
    // Rejections never change state; only accepts (<=128) do. Per 512-wide
    // window: parallel filter vs accepted set -> alive mask; then every pop of
    // the first alive bit IS an accept (mask kept current by parallel re-test
    // after each accept). Serial chain length == n <= 128 total.
    int  n    = 0;      // uniform across block
    bool done = false;

    for (int cb = 0; cb < NCAND && !done; cb += TPB) {
        const int idx = cb + tid;
        const unsigned pay = (unsigned)keys[idx];
        const int en = (int)(pay & 511u);
        const int st = (int)((pay >> 9) & 511u);

        // filter vs current accepted set (broadcast LDS reads, divergent break ok)
        bool alive = true;
        for (int a = 0; a < n; ++a) {
            unsigned ap = acc_list[a];
            int ae = (int)(ap & 511u), as = (int)((ap >> 9) & 511u);
            if ((st < as && as <= en && ae > en) || (as < st && ae >= st && ae < en)) {
                alive = false; break;
            }
        }

        for (;;) {
            unsigned long long m = __ballot((int)alive);
            if ((tid & 63) == 0) amask[tid >> 6] = m;
            __syncthreads();                       // (A) mask visible
            int s = -1;
            #pragma unroll
            for (int w = 0; w < TPB / 64; ++w) {
                unsigned long long mw = amask[w];
                if (s < 0 && mw) s = (w << 6) + __ffsll((long long)mw) - 1;
            }
            __syncthreads();                       // (B) reads done before next write
            if (s < 0) break;                      // uniform: window exhausted

            unsigned spay = (unsigned)keys[cb + s];    // uniform-address broadcast
            int sen = (int)(spay & 511u), sst = (int)((spay >> 9) & 511u);
            if (tid == 0) acc_list[n] = spay;
            ++n;
            if (n == KOUT) { done = true; break; } // uniform

            if (alive) {
                alive = (tid != s) &&
                        !((st < sst && sst <= en && sen > en) ||
                          (sst < st && sen >= st && sen < en));
            }
        }
    }
    __syncthreads();

    // ---- 4. Final (start,end)-sort of the n selected (tail-fill acc_list[0])
    if (tid < KOUT) {
        unsigned pay = (tid < n) ? acc_list[tid] : acc_list[0];
        paybuf[tid] = pay;
        mkbuf[tid]  = ((pay & 0x3FFFFu) << 7) | (unsigned)tid; // stable tie-break
    }
    __syncthreads();
    if (tid < KOUT) {
        unsigned mk = mkbuf[tid];
        int rank = 0;
        for (int t2 = 0; t2 < KOUT; ++t2)
            rank += (mkbuf[t2] < mk) ? 1 : 0;
        out[sent * KOUT + rank] = (int)(paybuf[tid] >> 18);
    }
}

extern "C" void kernel_launch(void* const* d_in, const int* in_sizes, int n_in,
                              void* d_out, int out_size, void* d_ws, size_t ws_size,
                              hipStream_t stream) {
    const float* scores = (const float*)d_in[0];
    const int*   starts = (const int*)d_in[1];
    const int*   ends   = (const int*)d_in[2];
    int*         out    = (int*)d_out;

    extract_spans_kernel<<<NSENT, TPB, 0, stream>>>(scores, starts, ends, out);
}

// Round 3
// 194.406 us; speedup vs baseline: 1.4477x; 1.2891x over previous
//
#include <hip/hip_runtime.h>

#define NSENT 64
#define NCAND 8192
#define LMAX  512
#define KOUT  128
#define TPB   512
#define CHUNK 2048
#define NCHUNK (NCAND / CHUNK)   // 4

// ---------------------------------------------------------------------------
// Kernel A: 256 blocks (sentence s = bid>>2, chunk c = bid&3).
// Bitonic-sort 2048 u64 keys in LDS, write sorted chunk to ws.
// Key: high 32 = descending-orderable score bits, low 31 = (idx<<18)|(st<<9)|en
// ---------------------------------------------------------------------------
__global__ __launch_bounds__(TPB) void sort_chunks_kernel(
    const float* __restrict__ scores,
    const int*   __restrict__ starts,
    const int*   __restrict__ ends,
    unsigned long long* __restrict__ ws)
{
    __shared__ unsigned long long lk[CHUNK];
    const int  bid   = blockIdx.x;
    const int  sent  = bid >> 2;
    const int  chunk = bid & 3;
    const int  tid   = threadIdx.x;
    const long gbase = (long)sent * NCAND + (long)chunk * CHUNK;

    for (int i = tid; i < CHUNK; i += TPB) {
        unsigned u  = __float_as_uint(scores[gbase + i]);
        unsigned o  = (u & 0x80000000u) ? ~u : (u | 0x80000000u); // asc-orderable
        unsigned d  = ~o;                                          // descending
        unsigned st = (unsigned)starts[gbase + i];
        unsigned en = (unsigned)ends[gbase + i];
        unsigned gi = (unsigned)(chunk * CHUNK + i);               // idx in sentence
        lk[i] = ((unsigned long long)d << 32) | (gi << 18) | (st << 9) | en;
    }

    for (int k = 2; k <= CHUNK; k <<= 1) {
        for (int j = k >> 1; j > 0; j >>= 1) {
            __syncthreads();
            for (int p = tid; p < CHUNK / 2; p += TPB) {
                int low = p & (j - 1);
                int i   = ((p - low) << 1) | low;
                int q   = i | j;
                unsigned long long a = lk[i];
                unsigned long long b = lk[q];
                bool up = ((i & k) == 0);
                if ((a > b) == up) { lk[i] = b; lk[q] = a; }
            }
        }
    }
    __syncthreads();

    unsigned long long* wo = ws + (long)bid * CHUNK;
    for (int i = tid; i < CHUNK; i += TPB) wo[i] = lk[i];
}

// ---------------------------------------------------------------------------
// Kernel B: 64 blocks (one per sentence). Merge 4 sorted chunks (merge-path,
// 2 stages, in-place LDS via register staging), then window-parallel greedy
// non-crossing selection, then rank-sort of the <=128 selected.
// ---------------------------------------------------------------------------
__global__ __launch_bounds__(TPB) void merge_greedy_kernel(
    const unsigned long long* __restrict__ ws,
    int* __restrict__ out)
{
    __shared__ unsigned long long keys[NCAND];   // 64 KiB
    __shared__ unsigned acc_list[KOUT];
    __shared__ unsigned long long amask[TPB/64];
    __shared__ unsigned mkbuf[KOUT];
    __shared__ unsigned paybuf[KOUT];

    const int sent = blockIdx.x;
    const int tid  = threadIdx.x;
    const unsigned long long* wi = ws + (long)sent * NCAND;

    for (int i = tid; i < NCAND; i += TPB) keys[i] = wi[i];
    __syncthreads();

    // ---- stage 1: merge (c0,c1)->[0,4096), (c2,c3)->[4096,8192) ------------
    {
        const int pair = tid >> 8;              // 256 threads per pair
        const int o    = (tid & 255) * 16;      // output offset within pair
        const unsigned long long* A = keys + pair * 4096;
        const unsigned long long* B = A + CHUNK;
        int lo = (o > CHUNK) ? o - CHUNK : 0;
        int hi = (o < CHUNK) ? o : CHUNK;
        while (lo < hi) {                        // smallest i : A[i] > B[o-1-i]
            int mid = (lo + hi) >> 1;
            if (A[mid] <= B[o - 1 - mid]) lo = mid + 1; else hi = mid;
        }
        int i = lo, j = o - lo;
        unsigned long long r[16];
        #pragma unroll
        for (int x = 0; x < 16; ++x) {
            bool ta = (j >= CHUNK) || (i < CHUNK && A[i] <= B[j]);
            r[x] = ta ? A[i++] : B[j++];
        }
        __syncthreads();                         // all reads done
        unsigned long long* O = keys + pair * 4096 + o;
        #pragma unroll
        for (int x = 0; x < 16; ++x) O[x] = r[x];
    }
    __syncthreads();

    // ---- stage 2: merge [0,4096)+[4096,8192) -> [0,8192) -------------------
    {
        const int o = tid * 16;
        const unsigned long long* A = keys;
        const unsigned long long* B = keys + 4096;
        int lo = (o > 4096) ? o - 4096 : 0;
        int hi = (o < 4096) ? o : 4096;
        while (lo < hi) {
            int mid = (lo + hi) >> 1;
            if (A[mid] <= B[o - 1 - mid]) lo = mid + 1; else hi = mid;
        }
        int i = lo, j = o - lo;
        unsigned long long r[16];
        #pragma unroll
        for (int x = 0; x < 16; ++x) {
            bool ta = (j >= 4096) || (i < 4096 && A[i] <= B[j]);
            r[x] = ta ? A[i++] : B[j++];
        }
        __syncthreads();
        #pragma unroll
        for (int x = 0; x < 16; ++x) keys[o + x] = r[x];
    }
    __syncthreads();

    // ---- greedy non-crossing selection (window-parallel) -------------------
    int  n    = 0;
    bool done = false;
    for (int cb = 0; cb < NCAND && !done; cb += TPB) {
        const int idx = cb + tid;
        const unsigned pay = (unsigned)keys[idx];
        const int en = (int)(pay & 511u);
        const int st = (int)((pay >> 9) & 511u);

        bool alive = true;
        for (int a = 0; a < n; ++a) {
            unsigned ap = acc_list[a];
            int ae = (int)(ap & 511u), as = (int)((ap >> 9) & 511u);
            if ((st < as && as <= en && ae > en) || (as < st && ae >= st && ae < en)) {
                alive = false; break;
            }
        }

        for (;;) {
            unsigned long long m = __ballot((int)alive);
            if ((tid & 63) == 0) amask[tid >> 6] = m;
            __syncthreads();
            int s = -1;
            #pragma unroll
            for (int w = 0; w < TPB / 64; ++w) {
                unsigned long long mw = amask[w];
                if (s < 0 && mw) s = (w << 6) + __ffsll((long long)mw) - 1;
            }
            __syncthreads();
            if (s < 0) break;

            unsigned spay = (unsigned)keys[cb + s];
            int sen = (int)(spay & 511u), sst = (int)((spay >> 9) & 511u);
            if (tid == 0) acc_list[n] = spay;
            ++n;
            if (n == KOUT) { done = true; break; }

            if (alive) {
                alive = (tid != s) &&
                        !((st < sst && sst <= en && sen > en) ||
                          (sst < st && sen >= st && sen < en));
            }
        }
    }
    __syncthreads();

    // ---- final (start,end) rank-sort + output ------------------------------
    if (tid < KOUT) {
        unsigned pay = (tid < n) ? acc_list[tid] : acc_list[0];
        paybuf[tid] = pay;
        mkbuf[tid]  = ((pay & 0x3FFFFu) << 7) | (unsigned)tid;
    }
    __syncthreads();
    if (tid < KOUT) {
        unsigned mk = mkbuf[tid];
        int rank = 0;
        for (int t2 = 0; t2 < KOUT; ++t2)
            rank += (mkbuf[t2] < mk) ? 1 : 0;
        out[sent * KOUT + rank] = (int)(paybuf[tid] >> 18);
    }
}

// ---------------------------------------------------------------------------
// Fallback monolithic kernel (round-2, known-correct) if ws is too small.
// ---------------------------------------------------------------------------
__global__ __launch_bounds__(TPB) void extract_spans_mono(
    const float* __restrict__ scores,
    const int*   __restrict__ starts,
    const int*   __restrict__ ends,
    int*         __restrict__ out)
{
    __shared__ unsigned long long keys[NCAND];
    __shared__ unsigned acc_list[KOUT];
    __shared__ unsigned long long amask[TPB/64];
    __shared__ unsigned mkbuf[KOUT];
    __shared__ unsigned paybuf[KOUT];

    const int  sent = blockIdx.x;
    const int  tid  = threadIdx.x;
    const long base = (long)sent * NCAND;

    for (int i = tid; i < NCAND; i += TPB) {
        unsigned u = __float_as_uint(scores[base + i]);
        unsigned o = (u & 0x80000000u) ? ~u : (u | 0x80000000u);
        unsigned d = ~o;
        unsigned st = (unsigned)starts[base + i];
        unsigned en = (unsigned)ends[base + i];
        keys[i] = ((unsigned long long)d << 32) | ((unsigned)i << 18) | (st << 9) | en;
    }
    for (int k = 2; k <= NCAND; k <<= 1) {
        for (int j = k >> 1; j > 0; j >>= 1) {
            __syncthreads();
            for (int p = tid; p < NCAND / 2; p += TPB) {
                int low = p & (j - 1);
                int i   = ((p - low) << 1) | low;
                int q   = i | j;
                unsigned long long a = keys[i];
                unsigned long long b = keys[q];
                bool up = ((i & k) == 0);
                if ((a > b) == up) { keys[i] = b; keys[q] = a; }
            }
        }
    }
    __syncthreads();

    int  n    = 0;
    bool done = false;
    for (int cb = 0; cb < NCAND && !done; cb += TPB) {
        const unsigned pay = (unsigned)keys[cb + tid];
        const int en = (int)(pay & 511u);
        const int st = (int)((pay >> 9) & 511u);
        bool alive = true;
        for (int a = 0; a < n; ++a) {
            unsigned ap = acc_list[a];
            int ae = (int)(ap & 511u), as = (int)((ap >> 9) & 511u);
            if ((st < as && as <= en && ae > en) || (as < st && ae >= st && ae < en)) {
                alive = false; break;
            }
        }
        for (;;) {
            unsigned long long m = __ballot((int)alive);
            if ((tid & 63) == 0) amask[tid >> 6] = m;
            __syncthreads();
            int s = -1;
            #pragma unroll
            for (int w = 0; w < TPB / 64; ++w) {
                unsigned long long mw = amask[w];
                if (s < 0 && mw) s = (w << 6) + __ffsll((long long)mw) - 1;
            }
            __syncthreads();
            if (s < 0) break;
            unsigned spay = (unsigned)keys[cb + s];
            int sen = (int)(spay & 511u), sst = (int)((spay >> 9) & 511u);
            if (tid == 0) acc_list[n] = spay;
            ++n;
            if (n == KOUT) { done = true; break; }
            if (alive) {
                alive = (tid != s) &&
                        !((st < sst && sst <= en && sen > en) ||
                          (sst < st && sen >= st && sen < en));
            }
        }
    }
    __syncthreads();
    if (tid < KOUT) {
        unsigned pay = (tid < n) ? acc_list[tid] : acc_list[0];
        paybuf[tid] = pay;
        mkbuf[tid]  = ((pay & 0x3FFFFu) << 7) | (unsigned)tid;
    }
    __syncthreads();
    if (tid < KOUT) {
        unsigned mk = mkbuf[tid];
        int rank = 0;
        for (int t2 = 0; t2 < KOUT; ++t2)
            rank += (mkbuf[t2] < mk) ? 1 : 0;
        out[sent * KOUT + rank] = (int)(paybuf[tid] >> 18);
    }
}

extern "C" void kernel_launch(void* const* d_in, const int* in_sizes, int n_in,
                              void* d_out, int out_size, void* d_ws, size_t ws_size,
                              hipStream_t stream) {
    const float* scores = (const float*)d_in[0];
    const int*   starts = (const int*)d_in[1];
    const int*   ends   = (const int*)d_in[2];
    int*         out    = (int*)d_out;

    const size_t ws_needed = (size_t)NSENT * NCAND * sizeof(unsigned long long); // 4 MiB
    if (ws_size >= ws_needed) {
        unsigned long long* ws = (unsigned long long*)d_ws;
        sort_chunks_kernel<<<NSENT * NCHUNK, TPB, 0, stream>>>(scores, starts, ends, ws);
        merge_greedy_kernel<<<NSENT, TPB, 0, stream>>>(ws, out);
    } else {
        extract_spans_mono<<<NSENT, TPB, 0, stream>>>(scores, starts, ends, out);
    }
}